// Round 1
// baseline (181.153 us; speedup 1.0000x reference)
//
#include <hip/hip_runtime.h>
#include <hip/hip_bf16.h>
#include <math.h>

#define N_ROWS 4096
#define D_DIM  128
#define M_ROWS 8192
#define INV_T  10.0f
#define COL_SPLITS 8
#define COLS_PER_BLOCK (M_ROWS / COL_SPLITS)   // 1024

typedef __attribute__((ext_vector_type(8))) short bf16x8;
typedef __attribute__((ext_vector_type(4))) float f32x4;

// --- Kernel 1: row-normalize z=[z1;z2] -> bf16 zn, store 1/norm (fp32) ---
__global__ __launch_bounds__(256) void normalize_kernel(
    const float* __restrict__ z1, const float* __restrict__ z2,
    ushort* __restrict__ zn, float* __restrict__ invnorm)
{
    const int row  = blockIdx.x * 4 + (threadIdx.x >> 6);
    const int lane = threadIdx.x & 63;
    const float* src = (row < N_ROWS) ? (z1 + (size_t)row * D_DIM)
                                      : (z2 + (size_t)(row - N_ROWS) * D_DIM);
    float2 v = ((const float2*)src)[lane];
    float ss = v.x * v.x + v.y * v.y;
    #pragma unroll
    for (int m = 1; m < 64; m <<= 1) ss += __shfl_xor(ss, m, 64);
    float inv = 1.0f / fmaxf(sqrtf(ss), 1e-8f);
    if (lane == 0) invnorm[row] = inv;
    __hip_bfloat16 a = __float2bfloat16(v.x * inv);
    __hip_bfloat16 b = __float2bfloat16(v.y * inv);
    ushort2 o;
    o.x = *(const ushort*)&a;
    o.y = *(const ushort*)&b;
    ((ushort2*)zn)[(size_t)row * 64 + lane] = o;
}

// --- Kernel 2: pos_i = 2*cos(z1_i, z2_i)/T  (fp32, exact-ish) ---
__global__ __launch_bounds__(256) void pos_kernel(
    const float* __restrict__ z1, const float* __restrict__ z2,
    const float* __restrict__ invnorm, float* __restrict__ pos)
{
    const int i    = blockIdx.x * 4 + (threadIdx.x >> 6);
    const int lane = threadIdx.x & 63;
    float2 a = ((const float2*)(z1 + (size_t)i * D_DIM))[lane];
    float2 b = ((const float2*)(z2 + (size_t)i * D_DIM))[lane];
    float d = a.x * b.x + a.y * b.y;
    #pragma unroll
    for (int m = 1; m < 64; m <<= 1) d += __shfl_xor(d, m, 64);
    if (lane == 0) pos[i] = 2.0f * INV_T * d * invnorm[i] * invnorm[i + N_ROWS];
}

// --- Kernel 3: S[i] = sum_{j != i} exp(sim[i][j])  via bf16 MFMA ---
// Wave covers 16 rows x COLS_PER_BLOCK cols. A frags held in registers.
// 16x16x32 layouts: A[m=lane&15][k=(lane>>4)*8+j]; B[k][n=lane&15] same shape
// from zn rows (Gram => B^T rows = zn rows). C/D: col=lane&15, row=(lane>>4)*4+reg.
__global__ __launch_bounds__(256) void simsum_kernel(
    const short* __restrict__ zn, float* __restrict__ S)
{
    const int lane = threadIdx.x & 63;
    const int wave = threadIdx.x >> 6;
    const int rowBase = blockIdx.y * 64 + wave * 16;
    const int colBase = blockIdx.x * COLS_PER_BLOCK;
    const int m = lane & 15;
    const int q = lane >> 4;

    const short* arow = zn + (size_t)(rowBase + m) * D_DIM + q * 8;
    bf16x8 afrag[4];
    #pragma unroll
    for (int s = 0; s < 4; ++s)
        afrag[s] = *(const bf16x8*)(arow + s * 32);

    float rsum0 = 0.f, rsum1 = 0.f, rsum2 = 0.f, rsum3 = 0.f;
    const int grow0 = rowBase + q * 4;

    for (int ct = 0; ct < COLS_PER_BLOCK / 16; ++ct) {
        const int cb = colBase + ct * 16;
        const short* brow = zn + (size_t)(cb + m) * D_DIM + q * 8;
        f32x4 acc = {0.f, 0.f, 0.f, 0.f};
        #pragma unroll
        for (int s = 0; s < 4; ++s) {
            bf16x8 bfrag = *(const bf16x8*)(brow + s * 32);
            acc = __builtin_amdgcn_mfma_f32_16x16x32_bf16(afrag[s], bfrag, acc, 0, 0, 0);
        }
        const int gcol = cb + m;
        float e0 = __expf(INV_T * acc[0]);
        float e1 = __expf(INV_T * acc[1]);
        float e2 = __expf(INV_T * acc[2]);
        float e3 = __expf(INV_T * acc[3]);
        if (grow0 + 0 == gcol) e0 = 0.f;   // mask diagonal exactly
        if (grow0 + 1 == gcol) e1 = 0.f;
        if (grow0 + 2 == gcol) e2 = 0.f;
        if (grow0 + 3 == gcol) e3 = 0.f;
        rsum0 += e0; rsum1 += e1; rsum2 += e2; rsum3 += e3;
    }

    // reduce across the 16 lanes sharing q (cols); butterfly keeps groups intact
    #pragma unroll
    for (int msk = 1; msk < 16; msk <<= 1) {
        rsum0 += __shfl_xor(rsum0, msk, 64);
        rsum1 += __shfl_xor(rsum1, msk, 64);
        rsum2 += __shfl_xor(rsum2, msk, 64);
        rsum3 += __shfl_xor(rsum3, msk, 64);
    }
    if (m == 0) atomicAdd(&S[grow0 + 0], rsum0);
    if (m == 1) atomicAdd(&S[grow0 + 1], rsum1);
    if (m == 2) atomicAdd(&S[grow0 + 2], rsum2);
    if (m == 3) atomicAdd(&S[grow0 + 3], rsum3);
}

// --- Kernel 4: out = (1/M^2) * sum_i [ log(S_i + exp(pos_i)) - pos_i ] ---
__global__ __launch_bounds__(1024) void loss_kernel(
    const float* __restrict__ S, const float* __restrict__ pos,
    float* __restrict__ out)
{
    const int tid = threadIdx.x;
    float acc = 0.f;
    for (int i = tid; i < M_ROWS; i += 1024) {
        float p = pos[i & (N_ROWS - 1)];
        acc += logf(S[i] + __expf(p)) - p;
    }
    #pragma unroll
    for (int msk = 1; msk < 64; msk <<= 1) acc += __shfl_xor(acc, msk, 64);
    __shared__ float red[16];
    if ((tid & 63) == 0) red[tid >> 6] = acc;
    __syncthreads();
    if (tid == 0) {
        float t = 0.f;
        #pragma unroll
        for (int w = 0; w < 16; ++w) t += red[w];
        out[0] = t / ((float)M_ROWS * (float)M_ROWS);
    }
}

extern "C" void kernel_launch(void* const* d_in, const int* in_sizes, int n_in,
                              void* d_out, int out_size, void* d_ws, size_t ws_size,
                              hipStream_t stream)
{
    const float* z1 = (const float*)d_in[0];
    const float* z2 = (const float*)d_in[1];
    float* out = (float*)d_out;

    // workspace layout (all 256B-aligned):
    //   zn      : M*D bf16   = 2 MiB
    //   invnorm : M fp32     = 32 KiB
    //   pos     : N fp32     = 16 KiB
    //   S       : M fp32     = 32 KiB
    char* w = (char*)d_ws;
    short* zn      = (short*)(w);
    float* invnorm = (float*)(w + 2097152);
    float* pos     = (float*)(w + 2097152 + 32768);
    float* S       = (float*)(w + 2097152 + 32768 + 16384);

    hipMemsetAsync(S, 0, M_ROWS * sizeof(float), stream);
    normalize_kernel<<<M_ROWS / 4, 256, 0, stream>>>(z1, z2, (ushort*)zn, invnorm);
    pos_kernel<<<N_ROWS / 4, 256, 0, stream>>>(z1, z2, invnorm, pos);
    simsum_kernel<<<dim3(COL_SPLITS, M_ROWS / 64), 256, 0, stream>>>(zn, S);
    loss_kernel<<<1, 1024, 0, stream>>>(S, pos, out);
}

// Round 2
// 112.664 us; speedup vs baseline: 1.6079x; 1.6079x over previous
//
#include <hip/hip_runtime.h>
#include <hip/hip_bf16.h>
#include <math.h>

#define N_ROWS 4096
#define D_DIM  128
#define M_ROWS 8192
#define INV_T  10.0f

typedef __attribute__((ext_vector_type(8))) short bf16x8;
typedef __attribute__((ext_vector_type(4))) float f32x4;

// --- Kernel 1: row-normalize z=[z1;z2] -> bf16 zn, store 1/norm (fp32) ---
__global__ __launch_bounds__(256) void normalize_kernel(
    const float* __restrict__ z1, const float* __restrict__ z2,
    ushort* __restrict__ zn, float* __restrict__ invnorm)
{
    const int row  = blockIdx.x * 4 + (threadIdx.x >> 6);
    const int lane = threadIdx.x & 63;
    const float* src = (row < N_ROWS) ? (z1 + (size_t)row * D_DIM)
                                      : (z2 + (size_t)(row - N_ROWS) * D_DIM);
    float2 v = ((const float2*)src)[lane];
    float ss = v.x * v.x + v.y * v.y;
    #pragma unroll
    for (int m = 1; m < 64; m <<= 1) ss += __shfl_xor(ss, m, 64);
    float inv = 1.0f / fmaxf(sqrtf(ss), 1e-8f);
    if (lane == 0) invnorm[row] = inv;
    __hip_bfloat16 a = __float2bfloat16(v.x * inv);
    __hip_bfloat16 b = __float2bfloat16(v.y * inv);
    ushort2 o;
    o.x = *(const ushort*)&a;
    o.y = *(const ushort*)&b;
    ((ushort2*)zn)[(size_t)row * 64 + lane] = o;
}

// --- Kernel 2: pos_i = 2*cos(z1_i, z2_i)/T  (fp32) ---
__global__ __launch_bounds__(256) void pos_kernel(
    const float* __restrict__ z1, const float* __restrict__ z2,
    const float* __restrict__ invnorm, float* __restrict__ pos)
{
    const int i    = blockIdx.x * 4 + (threadIdx.x >> 6);
    const int lane = threadIdx.x & 63;
    float2 a = ((const float2*)(z1 + (size_t)i * D_DIM))[lane];
    float2 b = ((const float2*)(z2 + (size_t)i * D_DIM))[lane];
    float d = a.x * b.x + a.y * b.y;
    #pragma unroll
    for (int m = 1; m < 64; m <<= 1) d += __shfl_xor(d, m, 64);
    if (lane == 0) pos[i] = 2.0f * INV_T * d * invnorm[i] * invnorm[i + N_ROWS];
}

// --- Kernel 3: S[i] = sum_{j != i} exp(sim[i][j]) via bf16 MFMA, LDS-staged ---
// Block: 4 waves, 128 rows (32/wave as two 16-row A-frag sets), 512 cols in
// 8 steps of 64 cols. LDS double buffer 2 x 16KiB, XOR-swizzled 16B chunks
// (chunk c stored at c^(row&15)) => minimal 8 dwords/bank on write and read.
__global__ __launch_bounds__(256) void simsum_kernel(
    const short* __restrict__ zn, float* __restrict__ S)
{
    __shared__ uint4 lbuf[2][64 * 16];   // [buf][row*16 + chunk], 16KiB each
    const int lane = threadIdx.x & 63;
    const int w    = threadIdx.x >> 6;
    const int m    = lane & 15;
    const int q    = lane >> 4;
    const int rowBase = blockIdx.y * 128 + w * 32;
    const int colBase = blockIdx.x * 512;

    // A fragments: 2 row-sets x 4 K-steps, held in registers for whole kernel
    bf16x8 afrag[2][4];
    #pragma unroll
    for (int h = 0; h < 2; ++h) {
        const short* ar = zn + (size_t)(rowBase + h * 16 + m) * D_DIM + q * 8;
        #pragma unroll
        for (int s = 0; s < 4; ++s) afrag[h][s] = *(const bf16x8*)(ar + s * 32);
    }

    const int srr = lane >> 4;   // staging: row-within-4
    const int sc  = lane & 15;   // staging: 16B chunk index
    uint4 regs[4];

    auto gload = [&](int step) {
        #pragma unroll
        for (int k = 0; k < 4; ++k) {
            int lr   = w * 16 + k * 4 + srr;
            int grow = colBase + step * 64 + lr;
            regs[k] = *((const uint4*)(zn + (size_t)grow * D_DIM) + sc);
        }
    };
    auto swrite = [&](int buf) {
        #pragma unroll
        for (int k = 0; k < 4; ++k) {
            int lr = w * 16 + k * 4 + srr;
            lbuf[buf][lr * 16 + (sc ^ (lr & 15))] = regs[k];
        }
    };

    gload(0);
    swrite(0);
    gload(1);
    __syncthreads();

    float rsum[8] = {0.f, 0.f, 0.f, 0.f, 0.f, 0.f, 0.f, 0.f};
    int buf = 0;

    for (int step = 0; step < 8; ++step) {
        const short* lb = (const short*)lbuf[buf];
        #pragma unroll
        for (int ct = 0; ct < 4; ++ct) {
            f32x4 acc0 = {0.f, 0.f, 0.f, 0.f};
            f32x4 acc1 = {0.f, 0.f, 0.f, 0.f};
            #pragma unroll
            for (int s = 0; s < 4; ++s) {
                bf16x8 bfrag = *(const bf16x8*)(lb + (ct * 16 + m) * D_DIM
                                                + (((q + s * 4) ^ m) * 8));
                acc0 = __builtin_amdgcn_mfma_f32_16x16x32_bf16(afrag[0][s], bfrag, acc0, 0, 0, 0);
                acc1 = __builtin_amdgcn_mfma_f32_16x16x32_bf16(afrag[1][s], bfrag, acc1, 0, 0, 0);
            }
            const int col = colBase + step * 64 + ct * 16 + m;
            #pragma unroll
            for (int r = 0; r < 4; ++r) {
                const int row0 = rowBase + q * 4 + r;
                float e0 = __expf(INV_T * acc0[r]);
                float e1 = __expf(INV_T * acc1[r]);
                if (row0 == col)      e0 = 0.f;   // mask diagonal exactly
                if (row0 + 16 == col) e1 = 0.f;
                rsum[r]     += e0;
                rsum[4 + r] += e1;
            }
        }
        if (step + 1 < 8) {
            swrite(buf ^ 1);
            if (step + 2 < 8) gload(step + 2);
        }
        __syncthreads();
        buf ^= 1;
    }

    #pragma unroll
    for (int msk = 1; msk < 16; msk <<= 1) {
        #pragma unroll
        for (int r = 0; r < 8; ++r) rsum[r] += __shfl_xor(rsum[r], msk, 64);
    }
    if (m < 4) {
        atomicAdd(&S[rowBase + q * 4 + m],      rsum[m]);
        atomicAdd(&S[rowBase + 16 + q * 4 + m], rsum[4 + m]);
    }
}

// --- Kernel 4: out = (1/M^2) * sum_i [ log(S_i + exp(pos_i)) - pos_i ] ---
__global__ __launch_bounds__(1024) void loss_kernel(
    const float* __restrict__ S, const float* __restrict__ pos,
    float* __restrict__ out)
{
    const int tid = threadIdx.x;
    float acc = 0.f;
    for (int i = tid; i < M_ROWS; i += 1024) {
        float p = pos[i & (N_ROWS - 1)];
        acc += logf(S[i] + __expf(p)) - p;
    }
    #pragma unroll
    for (int msk = 1; msk < 64; msk <<= 1) acc += __shfl_xor(acc, msk, 64);
    __shared__ float red[16];
    if ((tid & 63) == 0) red[tid >> 6] = acc;
    __syncthreads();
    if (tid == 0) {
        float t = 0.f;
        #pragma unroll
        for (int wv = 0; wv < 16; ++wv) t += red[wv];
        out[0] = t / ((float)M_ROWS * (float)M_ROWS);
    }
}

extern "C" void kernel_launch(void* const* d_in, const int* in_sizes, int n_in,
                              void* d_out, int out_size, void* d_ws, size_t ws_size,
                              hipStream_t stream)
{
    const float* z1 = (const float*)d_in[0];
    const float* z2 = (const float*)d_in[1];
    float* out = (float*)d_out;

    char* wsp = (char*)d_ws;
    short* zn      = (short*)(wsp);
    float* invnorm = (float*)(wsp + 2097152);
    float* pos     = (float*)(wsp + 2097152 + 32768);
    float* S       = (float*)(wsp + 2097152 + 32768 + 16384);

    hipMemsetAsync(S, 0, M_ROWS * sizeof(float), stream);
    normalize_kernel<<<M_ROWS / 4, 256, 0, stream>>>(z1, z2, (ushort*)zn, invnorm);
    pos_kernel<<<N_ROWS / 4, 256, 0, stream>>>(z1, z2, invnorm, pos);
    simsum_kernel<<<dim3(16, 64), 256, 0, stream>>>(zn, S);
    loss_kernel<<<1, 1024, 0, stream>>>(S, pos, out);
}